// Round 6
// baseline (411.542 us; speedup 1.0000x reference)
//
#include <hip/hip_runtime.h>

// ---------------- constants ----------------
#define BB   512   // batch
#define SS   256   // seq len
#define EE   128   // emb dim
#define HH   128   // per-dir hidden
#define LL   59    // labels
#define STARTL 57
#define STOPL  58
#define VOCAB 50000

typedef float  f32x4  __attribute__((ext_vector_type(4)));
typedef short  bf16x8 __attribute__((ext_vector_type(8)));
typedef short  s16x4  __attribute__((ext_vector_type(4)));

__device__ __forceinline__ short f2bf(float f) {
    unsigned u = __float_as_uint(f);
    u += 0x7FFFu + ((u >> 16) & 1u);   // RNE
    return (short)(u >> 16);
}
__device__ __forceinline__ float bf2f(unsigned short s) {
    return __uint_as_float(((unsigned)s) << 16);
}
__device__ __forceinline__ float sigf(float x) {
    float e = __builtin_amdgcn_exp2f(-1.44269504f * x);
    return __builtin_amdgcn_rcpf(1.0f + e);
}
__device__ __forceinline__ float tanhf_(float x) {
    float e = __builtin_amdgcn_exp2f(2.88539008f * x);
    return 1.0f - 2.0f * __builtin_amdgcn_rcpf(e + 1.0f);
}
__device__ __forceinline__ float wmax64(float v) {
    #pragma unroll
    for (int o = 32; o; o >>= 1) v = fmaxf(v, __shfl_xor(v, o));
    return v;
}
__device__ __forceinline__ float wsum64(float v) {
    #pragma unroll
    for (int o = 32; o; o >>= 1) v += __shfl_xor(v, o);
    return v;
}
__device__ __forceinline__ float rlane(float v, int i) {
    return __uint_as_float(__builtin_amdgcn_readlane(__float_as_uint(v), i));
}
// LDS-only barrier: global ops stay in flight across it.
__device__ __forceinline__ void bar_lds() {
    asm volatile("s_waitcnt lgkmcnt(0)\n\ts_barrier" ::: "memory");
}

// ---------------- kernel 1: fused BiLSTM (wave-specialized, R2 core) ----------------
// R15: conv_k ELIMINATED. Weights converted f32->bf16 inline at setup;
// embeddings gathered as f32 (raw f32x4 in registers, converted at use so
// the vmcnt wait sits ~1400 cyc after issue). Same f2bf on same values ->
// bit-identical gx/h. Core recurrence untouched (best measured 193.5 us;
// R3 showed it is barrier-chain-bound, occupancy-invariant).
__global__ __launch_bounds__(512, 2) void lstm_f(
    const int* __restrict__ x, const float* __restrict__ embed,
    const float* __restrict__ Wih_f, const float* __restrict__ Whh_f,
    const float* __restrict__ bih_f, const float* __restrict__ bhh_f,
    const float* __restrict__ Wih_b, const float* __restrict__ Whh_b,
    const float* __restrict__ bih_b, const float* __restrict__ bhh_b,
    const float* __restrict__ h0, const float* __restrict__ c0,
    const float* __restrict__ Wout,
    unsigned short* __restrict__ fpF, unsigned short* __restrict__ fpB)
{
    const int tid = threadIdx.x;
    const int w = tid >> 6, l = tid & 63, qd = l >> 4, n = l & 15;
    const int rt = blockIdx.x & 127, dir = blockIdx.x >> 7;
    const int b0 = rt * 4;
    unsigned short* fp = dir ? fpB : fpF;

    const float* Whh = dir ? Whh_b : Whh_f;
    const float* Wih = dir ? Wih_b : Wih_f;
    const float* bi  = dir ? bih_b : bih_f;
    const float* bh  = dir ? bhh_b : bhh_f;

    __shared__ __align__(16) short hbuf[2][2048];     // [ts&1][tile-row 0..15][8]; pads stay 0
    __shared__ __align__(16) float gxb[2][4][2048];   // [group&1][tau][slot][batch][gate] f32
    __shared__ int xsh[4 * 256];                      // [j 0..3][t]

    // zero both hbuf buffers + stage x tile
    #pragma unroll
    for (int i = 0; i < 2; ++i) ((s16x4*)hbuf)[tid + i * 512] = (s16x4)0;
    #pragma unroll
    for (int i = 0; i < 2; ++i) {
        const int k = tid + i * 512;
        xsh[k] = x[(size_t)(b0 + (k >> 8)) * SS + (k & 255)];
    }

    // f32 row -> bf16x8 fragment (same f2bf as the old conv_k)
    auto ldfrag = [&](const float* p) {
        const float4 lo = *(const float4*)p, hi = *(const float4*)(p + 4);
        bf16x8 v;
        v[0] = f2bf(lo.x); v[1] = f2bf(lo.y); v[2] = f2bf(lo.z); v[3] = f2bf(lo.w);
        v[4] = f2bf(hi.x); v[5] = f2bf(hi.y); v[6] = f2bf(hi.z); v[7] = f2bf(hi.w);
        return v;
    };

    if (w < 4) {
        // ---------- h-wave: slots 2w, 2w+1 ----------
        const int s0 = 2 * w, s1 = 2 * w + 1;
        bf16x8 fh0[4][4], fh1[4][4];
        #pragma unroll
        for (int g = 0; g < 4; ++g) {
            #pragma unroll
            for (int kk = 0; kk < 4; ++kk) {
                fh0[g][kk] = ldfrag(Whh + (size_t)(g * 128 + 16 * s0 + n) * 128 + kk * 32 + qd * 8);
                fh1[g][kk] = ldfrag(Whh + (size_t)(g * 128 + 16 * s1 + n) * 128 + kk * 32 + qd * 8);
            }
        }
        bf16x8 wb[4];
        {
            const int col = w * 16 + n;     // col-tiles 0..3 cover 64 >= LL
            #pragma unroll
            for (int kk = 0; kk < 4; ++kk) {
                bf16x8 v = (bf16x8)0;
                if (col < LL) {
                    const float* p = Wout + (size_t)col * 256 + dir * 128 + kk * 32 + qd * 8;
                    #pragma unroll
                    for (int j = 0; j < 8; ++j) v[j] = f2bf(p[j]);
                }
                wb[kk] = v;
            }
        }
        float cst0 = c0[((size_t)dir * BB + b0 + qd) * HH + 16 * s0 + n];
        float cst1 = c0[((size_t)dir * BB + b0 + qd) * HH + 16 * s1 + n];

        __syncthreads();   // B1: zeros + xsh visible
        {   // h0 -> hbuf[0] tile-rows {0,4,8,12} (512 thr = 4 rows x 128 cols)
            const int j = tid >> 7, c = tid & 127;
            hbuf[0][((c >> 3) * 16 + 4 * j) * 8 + (c & 7)] =
                f2bf(h0[((size_t)dir * BB + b0 + j) * HH + c]);
        }
        __syncthreads();   // B2: hbuf[0] + gxb[group 0] ready

        const int hid0 = 16 * s0 + n, hc0 = hid0 >> 3, ho0 = hid0 & 7;
        const int hid1 = 16 * s1 + n, hc1 = hid1 >> 3, ho1 = hid1 & 7;
        const int gs0 = (s0 * 64 + qd * 16 + n) * 4;
        const int gs1 = (s1 * 64 + qd * 16 + n) * 4;

        // persistent accumulators: elements 1..3 correspond to zero-padded
        // hbuf rows -> they stay 0 forever; only element 0 is read.
        f32x4 a0[4], a1[4], pa;
        #pragma unroll
        for (int g = 0; g < 4; ++g) {
            a0[g] = (f32x4){0.f, 0.f, 0.f, 0.f};
            a1[g] = (f32x4){0.f, 0.f, 0.f, 0.f};
        }
        pa = (f32x4){0.f, 0.f, 0.f, 0.f};

        // incremental emission pointer: dir=0 walks tep=0..SS-1, dir=1 walks SS-1..0
        unsigned short* fpp = fp + ((size_t)(b0 + qd) * SS + (dir ? SS - 1 : 0)) * 64
                            + w * 16 + n;
        const ptrdiff_t fpd = dir ? -64 : 64;

        for (int ts = 0; ts < SS; ++ts) {
            const int cur = ts & 1, nxt = cur ^ 1;
            const int gbuf = (ts >> 2) & 1, tau = ts & 3;

            const f32x4 g0 = *(const f32x4*)&gxb[gbuf][tau][gs0];
            const f32x4 g1 = *(const f32x4*)&gxb[gbuf][tau][gs1];

            bf16x8 ah[4];
            #pragma unroll
            for (int kk = 0; kk < 4; ++kk)
                ah[kk] = *(const bf16x8*)&hbuf[cur][((kk * 4 + qd) * 16 + n) * 8];

            a0[0][0] = g0[0]; a0[1][0] = g0[1]; a0[2][0] = g0[2]; a0[3][0] = g0[3];
            a1[0][0] = g1[0]; a1[1][0] = g1[1]; a1[2][0] = g1[2]; a1[3][0] = g1[3];

            #pragma unroll
            for (int kk = 0; kk < 4; ++kk) {
                #pragma unroll
                for (int g = 0; g < 4; ++g) {
                    a0[g] = __builtin_amdgcn_mfma_f32_16x16x32_bf16(ah[kk], fh0[g][kk], a0[g], 0, 0, 0);
                    a1[g] = __builtin_amdgcn_mfma_f32_16x16x32_bf16(ah[kk], fh1[g][kk], a1[g], 0, 0, 0);
                }
            }

            if (ts > 0) {   // project h_{ts-1} (reuses ah)
                pa[0] = 0.f;
                #pragma unroll
                for (int kk = 0; kk < 4; ++kk)
                    pa = __builtin_amdgcn_mfma_f32_16x16x32_bf16(ah[kk], wb[kk], pa, 0, 0, 0);
                *fpp = (unsigned short)f2bf(pa[0]);
                fpp += fpd;
            }

            {   // gates (r=0 real), both slots
                const float iv0 = sigf(a0[0][0]), fv0 = sigf(a0[1][0]);
                const float gv0 = tanhf_(a0[2][0]), ov0 = sigf(a0[3][0]);
                const float cc0 = fv0 * cst0 + iv0 * gv0;
                cst0 = cc0;
                hbuf[nxt][(hc0 * 16 + 4 * qd) * 8 + ho0] = f2bf(ov0 * tanhf_(cc0));
                const float iv1 = sigf(a1[0][0]), fv1 = sigf(a1[1][0]);
                const float gv1 = tanhf_(a1[2][0]), ov1 = sigf(a1[3][0]);
                const float cc1 = fv1 * cst1 + iv1 * gv1;
                cst1 = cc1;
                hbuf[nxt][(hc1 * 16 + 4 * qd) * 8 + ho1] = f2bf(ov1 * tanhf_(cc1));
            }
            bar_lds();
        }

        {   // project h_{SS-1} (in hbuf[0], SS even)
            pa[0] = 0.f;
            #pragma unroll
            for (int kk = 0; kk < 4; ++kk) {
                const bf16x8 a = *(const bf16x8*)&hbuf[0][((kk * 4 + qd) * 16 + n) * 8];
                pa = __builtin_amdgcn_mfma_f32_16x16x32_bf16(a, wb[kk], pa, 0, 0, 0);
            }
            *fpp = (unsigned short)f2bf(pa[0]);
        }
    } else {
        // ---------- x-wave: slots 2(w-4), 2(w-4)+1; 4-ts-batched (M = 4 batch x 4 tau) ----------
        const int s0 = 2 * (w - 4), s1 = s0 + 1;
        bf16x8 fx0[4][4], fx1[4][4]; float bs0[4], bs1[4];
        #pragma unroll
        for (int g = 0; g < 4; ++g) {
            bs0[g] = bi[g * 128 + 16 * s0 + n] + bh[g * 128 + 16 * s0 + n];
            bs1[g] = bi[g * 128 + 16 * s1 + n] + bh[g * 128 + 16 * s1 + n];
            #pragma unroll
            for (int kk = 0; kk < 4; ++kk) {
                fx0[g][kk] = ldfrag(Wih + (size_t)(g * 128 + 16 * s0 + n) * 128 + kk * 32 + qd * 8);
                fx1[g][kk] = ldfrag(Wih + (size_t)(g * 128 + 16 * s1 + n) * 128 + kk * 32 + qd * 8);
            }
        }
        const int gs0 = (s0 * 64 + qd * 16 + n) * 4;
        const int gs1 = (s1 * 64 + qd * 16 + n) * 4;
        const int jb   = n >> 2;          // A row n -> batch j = n>>2
        const int tau  = n & 3;           //           tau = n&3
        const int jrow = jb * 256;

        // raw f32 emb frags for group G (loads only -> vmcnt waits at cvt site)
        auto loadfrag = [&](int G, f32x4* ef) {
            const int t  = 4 * G + tau;
            const int te = dir ? (SS - 1 - t) : t;
            const int xi = xsh[jrow + te];
            const float* er = embed + (size_t)xi * EE + qd * 8;
            #pragma unroll
            for (int kk = 0; kk < 4; ++kk) {
                ef[kk * 2]     = *(const f32x4*)(er + kk * 32);
                ef[kk * 2 + 1] = *(const f32x4*)(er + kk * 32 + 4);
            }
        };
        auto cvt = [&](const f32x4* ef, bf16x8* e) {
            #pragma unroll
            for (int kk = 0; kk < 4; ++kk) {
                const f32x4 lo = ef[kk * 2], hi = ef[kk * 2 + 1];
                bf16x8 v;
                v[0] = f2bf(lo[0]); v[1] = f2bf(lo[1]); v[2] = f2bf(lo[2]); v[3] = f2bf(lo[3]);
                v[4] = f2bf(hi[0]); v[5] = f2bf(hi[1]); v[6] = f2bf(hi[2]); v[7] = f2bf(hi[3]);
                e[kk] = v;
            }
        };
        // one slot's gx for a whole 4-ts group -> gxb[buf][0..3]
        auto computeS = [&](const bf16x8* e, const bf16x8 (*fx)[4],
                            const float* bs, int gsv, int buf) {
            f32x4 c[4] = { {0,0,0,0}, {0,0,0,0}, {0,0,0,0}, {0,0,0,0} };
            #pragma unroll
            for (int g = 0; g < 4; ++g) {
                #pragma unroll
                for (int kk = 0; kk < 4; ++kk)
                    c[g] = __builtin_amdgcn_mfma_f32_16x16x32_bf16(e[kk], fx[g][kk], c[g], 0, 0, 0);
            }
            #pragma unroll
            for (int r = 0; r < 4; ++r) {
                f32x4 p = { c[0][r] + bs[0], c[1][r] + bs[1],
                            c[2][r] + bs[2], c[3][r] + bs[3] };
                *(f32x4*)&gxb[buf][r][gsv] = p;
            }
        };

        __syncthreads();   // B1: xsh visible
        f32x4 eA[8], eB[8];
        loadfrag(0, eA);                       // group 0 frags (f32)
        {
            bf16x8 e0[4]; cvt(eA, e0);
            computeS(e0, fx0, bs0, gs0, 0);    // gxb[0] <- group 0 (pre-loop stall, once)
            computeS(e0, fx1, bs1, gs1, 0);
        }
        loadfrag(1, eB);                       // group 1 frags
        __syncthreads();   // B2

        // at group G (h consumes ts 4G..4G+3): produce group G+1 into buf (G+1)&1
        // (slot0 in interval 0, slot1 in interval 1), prefetch frags for G+2.
        auto xgroup = [&](int G, f32x4* use, f32x4* pre) {
            if (G + 2 < SS / 4) loadfrag(G + 2, pre);
            bf16x8 e[4];
            if (G + 1 < SS / 4) { cvt(use, e); computeS(e, fx0, bs0, gs0, (G + 1) & 1); }
            bar_lds();
            if (G + 1 < SS / 4) computeS(e, fx1, bs1, gs1, (G + 1) & 1);
            bar_lds();
            bar_lds();
            bar_lds();
        };
        for (int G = 0; G < SS / 4; G += 2) {
            xgroup(G,     eB, eA);
            xgroup(G + 1, eA, eB);
        }
    }
}

// ---------------- kernel 2: CRF fwd/bwd split + gold + reduce ----------------
// R15: per-step dot now via LDS broadcast instead of 59x v_readlane.
// R4->R5 isolation measured u=592 cyc/step for the readlane form (~2.4x the
// issue model) -> v_readlane->SGPR->v_fmac hazards dominate. New form:
// ds_write ea (1 op), 15x ds_read_b128 broadcast (same addr all lanes,
// conflict-free), 59x pure-VGPR v_fmac. Accumulation order identical
// (d_k gets i === k mod 8) -> bit-identical result.
__global__ __launch_bounds__(128, 1) void crf_k(
    const unsigned short* __restrict__ fpF, const unsigned short* __restrict__ fpB,
    const float* __restrict__ bout, const int* __restrict__ y,
    const float* __restrict__ trans, float* __restrict__ out)
{
    const int tid = threadIdx.x;
    const int wv = tid >> 6;          // 0 = alpha wave, 1 = beta+gold wave
    const int j = tid & 63;
    const int b = blockIdx.x;
    const size_t bS = (size_t)b * SS;
    const bool valid = (j < LL);
    const int  jr = valid ? j : (LL - 1);
    const float L2E = 1.44269504f, LN2 = 0.69314718f;

    __shared__ __align__(16) float eash[2][64];
    __shared__ float exch[64];
    __shared__ float gshare;

    // per-lane transition table (log2-exponentiated):
    //   wave 0 (alpha): row jr -> etr[i] = 2^(T[jr,i]*L2E)
    //   wave 1 (beta):  col jr -> etr[i] = 2^(T[i,jr]*L2E)
    float etr[LL];
    #pragma unroll
    for (int i = 0; i < LL; ++i) {
        const float t = wv ? trans[i * LL + jr] : trans[jr * LL + i];
        etr[i] = valid ? __builtin_amdgcn_exp2f(t * L2E) : 0.0f;
    }
    const float bo = valid ? bout[jr] : 0.0f;

    // state (log2 domain): alpha for wave 0, beta for wave 1
    float st;
    if (wv == 0) st = valid ? ((j == STARTL) ? 0.0f : -10000.0f * L2E) : -1e30f;
    else         st = valid ? trans[STOPL * LL + jr] * L2E : -1e30f;
    float Kn = 0.0f;   // lagged stabilizer

    float* myea = &eash[wv][0];

    // LDS-broadcast dot: d_k += etr[i] * ea[i], i === k (mod 8) (same as R5)
    auto lsedot = [&](float ex) {
        myea[j] = ex;                       // ds_write; lgkm wait auto-inserted
        f32x4 e4[15];
        #pragma unroll
        for (int q = 0; q < 15; ++q) e4[q] = *(const f32x4*)(myea + 4 * q);
        float d0 = 0.f, d1 = 0.f, d2 = 0.f, d3 = 0.f;
        float d4 = 0.f, d5 = 0.f, d6 = 0.f, d7 = 0.f;
        #pragma unroll
        for (int i = 0; i < 56; i += 8) {
            d0 += etr[i]     * e4[(i    ) >> 2][(i    ) & 3];
            d1 += etr[i + 1] * e4[(i + 1) >> 2][(i + 1) & 3];
            d2 += etr[i + 2] * e4[(i + 2) >> 2][(i + 2) & 3];
            d3 += etr[i + 3] * e4[(i + 3) >> 2][(i + 3) & 3];
            d4 += etr[i + 4] * e4[(i + 4) >> 2][(i + 4) & 3];
            d5 += etr[i + 5] * e4[(i + 5) >> 2][(i + 5) & 3];
            d6 += etr[i + 6] * e4[(i + 6) >> 2][(i + 6) & 3];
            d7 += etr[i + 7] * e4[(i + 7) >> 2][(i + 7) & 3];
        }
        d0 += etr[56] * e4[14][0];
        d1 += etr[57] * e4[14][1];
        d2 += etr[58] * e4[14][2];
        return ((d0 + d1) + (d2 + d3)) + ((d4 + d5) + (d6 + d7));
    };

    // emission stream: wave 0 ascending t=0.., wave 1 descending t=255..
    auto tAt = [&](int u) { return wv ? (SS - 1 - u) : u; };

    float fF[8], fB[8];
    #pragma unroll
    for (int q = 0; q < 8; ++q) {
        const int t = tAt(q);
        fF[q] = bf2f(fpF[(bS + t) * 64 + j]);
        fB[q] = bf2f(fpB[(bS + t) * 64 + j]);
    }

    for (int u0 = 0; u0 < SS / 2; u0 += 8) {
        float nF[8], nB[8];
        #pragma unroll
        for (int q = 0; q < 8; ++q) { nF[q] = 0.0f; nB[q] = 0.0f; }
        if (u0 + 8 < SS / 2) {
            #pragma unroll
            for (int q = 0; q < 8; ++q) {
                const int t = tAt(u0 + 8 + q);
                nF[q] = bf2f(fpF[(bS + t) * 64 + j]);
                nB[q] = bf2f(fpB[(bS + t) * 64 + j]);
            }
        }
        float fs[8];
        #pragma unroll
        for (int q = 0; q < 8; ++q) fs[q] = (fF[q] + fB[q] + bo) * L2E;

        #pragma unroll
        for (int u = 0; u < 8; ++u) {
            if (wv == 0) {
                // alpha[j] <- fs[j] + LSE_i(alpha[i] + T[j,i])
                const float Kc = Kn;
                const float ea = __builtin_amdgcn_exp2f(st - Kc);
                Kn = fmaxf(rlane(st, 1), rlane(st, STARTL));
                const float dot = lsedot(ea);
                st = fs[u] + Kc + __builtin_amdgcn_logf(dot);   // v_log_f32 = log2
            } else {
                // beta[i] <- LSE_j( (fs[j] + beta[j]) + T[j,i] )
                const float g = fs[u] + st;
                const float Kc = Kn;
                const float eg = __builtin_amdgcn_exp2f(g - Kc);
                Kn = rlane(g, 1);
                const float dot = lsedot(eg);
                st = Kc + __builtin_amdgcn_logf(dot);
            }
        }
        #pragma unroll
        for (int q = 0; q < 8; ++q) { fF[q] = nF[q]; fB[q] = nB[q]; }
    }

    if (wv == 1) {
        // gold path score (whole 0..255 range, 64 lanes x 4)
        float g = 0.0f;
        #pragma unroll
        for (int q = 0; q < 4; ++q) {
            const int t  = q * 64 + j;
            const int yt = y[bS + t];
            const int yp = t ? y[bS + t - 1] : STARTL;
            g += bf2f(fpF[(bS + t) * 64 + yt]) + bf2f(fpB[(bS + t) * 64 + yt])
               + bout[yt] + trans[yt * LL + yp];
        }
        g = wsum64(g);
        if (j == 0) {
            g += trans[STOPL * LL + y[bS + SS - 1]];
            gshare = g;
        }
        exch[j] = st;      // beta_127 (log2)
    }
    __syncthreads();
    if (wv == 0) {
        // fwd = LN2 * LSE2_i(alpha_127[i] + beta_127[i])
        const float v2 = valid ? (st + exch[j]) : -1e30f;
        const float m2 = wmax64(v2);
        const float s  = wsum64(__builtin_amdgcn_exp2f(v2 - m2));
        const float fwd = LN2 * (m2 + __builtin_amdgcn_logf(s));
        if (j == 0) atomicAdd(out, fwd - gshare);
    }
}

// ---------------- launcher ----------------
extern "C" void kernel_launch(void* const* d_in, const int* in_sizes, int n_in,
                              void* d_out, int out_size, void* d_ws, size_t ws_size,
                              hipStream_t stream)
{
    (void)in_sizes; (void)n_in; (void)out_size; (void)ws_size;
    const int*   x      = (const int*)  d_in[0];
    const int*   y      = (const int*)  d_in[1];
    const float* embed  = (const float*)d_in[2];
    const float* Wih_f  = (const float*)d_in[3];
    const float* Whh_f  = (const float*)d_in[4];
    const float* bih_f  = (const float*)d_in[5];
    const float* bhh_f  = (const float*)d_in[6];
    const float* Wih_b  = (const float*)d_in[7];
    const float* Whh_b  = (const float*)d_in[8];
    const float* bih_b  = (const float*)d_in[9];
    const float* bhh_b  = (const float*)d_in[10];
    const float* Wout   = (const float*)d_in[11];
    const float* bout   = (const float*)d_in[12];
    const float* trans  = (const float*)d_in[13];
    const float* h0     = (const float*)d_in[14];
    const float* c0     = (const float*)d_in[15];

    const size_t MiB = 1ull << 20;
    unsigned short* fpF = (unsigned short*)d_ws;                      // 16 MiB
    unsigned short* fpB = (unsigned short*)((char*)d_ws + 16 * MiB);  // 16 MiB

    hipMemsetAsync(d_out, 0, sizeof(float), stream);
    lstm_f<<<256, 512, 0, stream>>>(x, embed,
                                    Wih_f, Whh_f, bih_f, bhh_f,
                                    Wih_b, Whh_b, bih_b, bhh_b,
                                    h0, c0, Wout, fpF, fpB);
    crf_k<<<BB, 128, 0, stream>>>(fpF, fpB, bout, y, trans, (float*)d_out);
}

// Round 8
// 332.729 us; speedup vs baseline: 1.2369x; 1.2369x over previous
//
#include <hip/hip_runtime.h>

// ---------------- constants ----------------
#define BB   512   // batch
#define SS   256   // seq len
#define EE   128   // emb dim
#define HH   128   // per-dir hidden
#define LL   59    // labels
#define STARTL 57
#define STOPL  58
#define VOCAB 50000

typedef float  f32x4  __attribute__((ext_vector_type(4)));
typedef short  bf16x8 __attribute__((ext_vector_type(8)));
typedef short  s16x4  __attribute__((ext_vector_type(4)));

__device__ __forceinline__ short f2bf(float f) {
    unsigned u = __float_as_uint(f);
    u += 0x7FFFu + ((u >> 16) & 1u);   // RNE
    return (short)(u >> 16);
}
__device__ __forceinline__ float bf2f(unsigned short s) {
    return __uint_as_float(((unsigned)s) << 16);
}
__device__ __forceinline__ float sigf(float x) {
    float e = __builtin_amdgcn_exp2f(-1.44269504f * x);
    return __builtin_amdgcn_rcpf(1.0f + e);
}
__device__ __forceinline__ float tanhf_(float x) {
    float e = __builtin_amdgcn_exp2f(2.88539008f * x);
    return 1.0f - 2.0f * __builtin_amdgcn_rcpf(e + 1.0f);
}
__device__ __forceinline__ float wmax64(float v) {
    #pragma unroll
    for (int o = 32; o; o >>= 1) v = fmaxf(v, __shfl_xor(v, o));
    return v;
}
__device__ __forceinline__ float wsum64(float v) {
    #pragma unroll
    for (int o = 32; o; o >>= 1) v += __shfl_xor(v, o);
    return v;
}
__device__ __forceinline__ float rlane(float v, int i) {
    return __uint_as_float(__builtin_amdgcn_readlane(__float_as_uint(v), i));
}
// LDS-only barrier: global ops stay in flight across it.
__device__ __forceinline__ void bar_lds() {
    asm volatile("s_waitcnt lgkmcnt(0)\n\ts_barrier" ::: "memory");
}

// ---------------- kernel 0: f32 -> bf16 tables + bias sums ----------------
// R7: restored. R6 proved inline conversion false economy: f32 embed gather +
// 16 extra VGPRs pushed x-waves over the 128 cap -> 75 MB scratch spills,
// lstm_f +85 us. The bf16 table costs ~10-13 us here and pays for itself.
__global__ __launch_bounds__(256) void conv_k(
    const float* __restrict__ embed,
    const float* __restrict__ Wih_f, const float* __restrict__ Wih_b,
    const float* __restrict__ Whh_f, const float* __restrict__ Whh_b,
    const float* __restrict__ bih_f, const float* __restrict__ bhh_f,
    const float* __restrict__ bih_b, const float* __restrict__ bhh_b,
    unsigned short* __restrict__ ebf, unsigned short* __restrict__ wix,
    unsigned short* __restrict__ whb, float* __restrict__ bsum)
{
    const int W1 = VOCAB * EE / 4;      // embed float4
    const int W2 = W1 + 2 * 16384;      // wix  (Wih both dirs)
    const int W3 = W2 + 2 * 16384;      // whb  (Whh both dirs)
    const int W4 = W3 + 1024;           // bias sums
    for (int i = blockIdx.x * blockDim.x + threadIdx.x; i < W4;
         i += gridDim.x * blockDim.x) {
        if (i < W1) {
            float4 v = ((const float4*)embed)[i];
            s16x4 s = { f2bf(v.x), f2bf(v.y), f2bf(v.z), f2bf(v.w) };
            ((s16x4*)ebf)[i] = s;
        } else if (i < W2) {
            const int j = i - W1, d = j >> 14, e = j & 16383;
            float4 v = ((const float4*)(d ? Wih_b : Wih_f))[e];
            s16x4 s = { f2bf(v.x), f2bf(v.y), f2bf(v.z), f2bf(v.w) };
            ((s16x4*)wix)[d * 16384 + e] = s;
        } else if (i < W3) {
            const int j = i - W2, d = j >> 14, e = j & 16383;
            float4 v = ((const float4*)(d ? Whh_b : Whh_f))[e];
            s16x4 s = { f2bf(v.x), f2bf(v.y), f2bf(v.z), f2bf(v.w) };
            ((s16x4*)whb)[d * 16384 + e] = s;
        } else {
            const int m = i - W3, d = m >> 9, c = m & 511;
            bsum[d * 512 + c] = d ? (bih_b[c] + bhh_b[c]) : (bih_f[c] + bhh_f[c]);
        }
    }
}

// ---------------- kernel 1: fused BiLSTM (wave-specialized, R5 base) ----------------
// R7 change: PROJECTION OFFLOADED to x-waves. The h-wave's barrier-to-barrier
// critical chain was: ds_reads -> 32 a-MFMAs -> 4 proj-MFMAs (serial chain) +
// fp store -> gates -> ds_write -> bar. Proj only needs hbuf[cur] (readable by
// any wave post-barrier), so x-wave ct projects h_{ts-1} for its 16-label
// col-tile during each interval (x-waves idle 2 of 4 intervals). Same ah
// fragments, same wb fragments, same seed -> bit-identical fp. h-wave per-ts
// chain sheds 4 MFMA issues + store addressing.
__global__ __launch_bounds__(512, 2) void lstm_f(
    const int* __restrict__ x, const unsigned short* __restrict__ ebf,
    const unsigned short* __restrict__ wix, const unsigned short* __restrict__ whb,
    const float* __restrict__ bsum,
    const float* __restrict__ h0, const float* __restrict__ c0,
    const float* __restrict__ Wout,
    unsigned short* __restrict__ fpF, unsigned short* __restrict__ fpB)
{
    const int tid = threadIdx.x;
    const int w = tid >> 6, l = tid & 63, qd = l >> 4, n = l & 15;
    const int rt = blockIdx.x & 127, dir = blockIdx.x >> 7;
    const int b0 = rt * 4;
    unsigned short* fp = dir ? fpB : fpF;

    __shared__ __align__(16) short hbuf[2][2048];     // [ts&1][tile-row 0..15][8]; pads stay 0
    __shared__ __align__(16) float gxb[2][4][2048];   // [group&1][tau][slot][batch][gate] f32
    __shared__ int xsh[4 * 256];                      // [j 0..3][t]

    // zero both hbuf buffers + stage x tile
    #pragma unroll
    for (int i = 0; i < 2; ++i) ((s16x4*)hbuf)[tid + i * 512] = (s16x4)0;
    #pragma unroll
    for (int i = 0; i < 2; ++i) {
        const int k = tid + i * 512;
        xsh[k] = x[(size_t)(b0 + (k >> 8)) * SS + (k & 255)];
    }

    if (w < 4) {
        // ---------- h-wave: slots 2w, 2w+1 (recurrence only) ----------
        const int s0 = 2 * w, s1 = 2 * w + 1;
        bf16x8 fh0[4][4], fh1[4][4];
        #pragma unroll
        for (int g = 0; g < 4; ++g) {
            #pragma unroll
            for (int kk = 0; kk < 4; ++kk) {
                fh0[g][kk] = *(const bf16x8*)(whb + dir * 65536
                             + (size_t)(g * 128 + 16 * s0 + n) * 128 + kk * 32 + qd * 8);
                fh1[g][kk] = *(const bf16x8*)(whb + dir * 65536
                             + (size_t)(g * 128 + 16 * s1 + n) * 128 + kk * 32 + qd * 8);
            }
        }
        float cst0 = c0[((size_t)dir * BB + b0 + qd) * HH + 16 * s0 + n];
        float cst1 = c0[((size_t)dir * BB + b0 + qd) * HH + 16 * s1 + n];

        __syncthreads();   // B1: zeros + xsh visible
        {   // h0 -> hbuf[0] tile-rows {0,4,8,12} (512 thr = 4 rows x 128 cols)
            const int j = tid >> 7, c = tid & 127;
            hbuf[0][((c >> 3) * 16 + 4 * j) * 8 + (c & 7)] =
                f2bf(h0[((size_t)dir * BB + b0 + j) * HH + c]);
        }
        __syncthreads();   // B2: hbuf[0] + gxb[group 0] ready

        const int hid0 = 16 * s0 + n, hc0 = hid0 >> 3, ho0 = hid0 & 7;
        const int hid1 = 16 * s1 + n, hc1 = hid1 >> 3, ho1 = hid1 & 7;
        const int gs0 = (s0 * 64 + qd * 16 + n) * 4;
        const int gs1 = (s1 * 64 + qd * 16 + n) * 4;

        // persistent accumulators: elements 1..3 correspond to zero-padded
        // hbuf rows -> they stay 0 forever; only element 0 is read.
        f32x4 a0[4], a1[4];
        #pragma unroll
        for (int g = 0; g < 4; ++g) {
            a0[g] = (f32x4){0.f, 0.f, 0.f, 0.f};
            a1[g] = (f32x4){0.f, 0.f, 0.f, 0.f};
        }

        for (int ts = 0; ts < SS; ++ts) {
            const int cur = ts & 1, nxt = cur ^ 1;
            const int gbuf = (ts >> 2) & 1, tau = ts & 3;

            const f32x4 g0 = *(const f32x4*)&gxb[gbuf][tau][gs0];
            const f32x4 g1 = *(const f32x4*)&gxb[gbuf][tau][gs1];

            bf16x8 ah[4];
            #pragma unroll
            for (int kk = 0; kk < 4; ++kk)
                ah[kk] = *(const bf16x8*)&hbuf[cur][((kk * 4 + qd) * 16 + n) * 8];

            a0[0][0] = g0[0]; a0[1][0] = g0[1]; a0[2][0] = g0[2]; a0[3][0] = g0[3];
            a1[0][0] = g1[0]; a1[1][0] = g1[1]; a1[2][0] = g1[2]; a1[3][0] = g1[3];

            #pragma unroll
            for (int kk = 0; kk < 4; ++kk) {
                #pragma unroll
                for (int g = 0; g < 4; ++g) {
                    a0[g] = __builtin_amdgcn_mfma_f32_16x16x32_bf16(ah[kk], fh0[g][kk], a0[g], 0, 0, 0);
                    a1[g] = __builtin_amdgcn_mfma_f32_16x16x32_bf16(ah[kk], fh1[g][kk], a1[g], 0, 0, 0);
                }
            }

            {   // gates (r=0 real), both slots — straight to the barrier
                const float iv0 = sigf(a0[0][0]), fv0 = sigf(a0[1][0]);
                const float gv0 = tanhf_(a0[2][0]), ov0 = sigf(a0[3][0]);
                const float cc0 = fv0 * cst0 + iv0 * gv0;
                cst0 = cc0;
                hbuf[nxt][(hc0 * 16 + 4 * qd) * 8 + ho0] = f2bf(ov0 * tanhf_(cc0));
                const float iv1 = sigf(a1[0][0]), fv1 = sigf(a1[1][0]);
                const float gv1 = tanhf_(a1[2][0]), ov1 = sigf(a1[3][0]);
                const float cc1 = fv1 * cst1 + iv1 * gv1;
                cst1 = cc1;
                hbuf[nxt][(hc1 * 16 + 4 * qd) * 8 + ho1] = f2bf(ov1 * tanhf_(cc1));
            }
            bar_lds();
        }
    } else {
        // ---------- x-wave: slots 2(w-4), 2(w-4)+1; 4-ts-batched + PROJECTION ----------
        const int ct = w - 4;             // proj col-tile: labels 16ct..16ct+15
        const int s0 = 2 * (w - 4), s1 = s0 + 1;
        bf16x8 fx0[4][4], fx1[4][4]; float bs0[4], bs1[4];
        #pragma unroll
        for (int g = 0; g < 4; ++g) {
            bs0[g] = bsum[dir * 512 + g * 128 + 16 * s0 + n];
            bs1[g] = bsum[dir * 512 + g * 128 + 16 * s1 + n];
            #pragma unroll
            for (int kk = 0; kk < 4; ++kk) {
                fx0[g][kk] = *(const bf16x8*)(wix + dir * 65536
                             + (size_t)(g * 128 + 16 * s0 + n) * 128 + kk * 32 + qd * 8);
                fx1[g][kk] = *(const bf16x8*)(wix + dir * 65536
                             + (size_t)(g * 128 + 16 * s1 + n) * 128 + kk * 32 + qd * 8);
            }
        }
        bf16x8 wbx[4];   // Wout fragments for col-tile ct (zero-padded >= LL)
        {
            const int col = ct * 16 + n;
            #pragma unroll
            for (int kk = 0; kk < 4; ++kk) {
                bf16x8 v = (bf16x8)0;
                if (col < LL) {
                    const float* p = Wout + (size_t)col * 256 + dir * 128 + kk * 32 + qd * 8;
                    #pragma unroll
                    for (int j = 0; j < 8; ++j) v[j] = f2bf(p[j]);
                }
                wbx[kk] = v;
            }
        }
        const int gs0 = (s0 * 64 + qd * 16 + n) * 4;
        const int gs1 = (s1 * 64 + qd * 16 + n) * 4;
        const int jb   = n >> 2;          // A row n -> batch j = n>>2
        const int tau  = n & 3;           //           tau = n&3
        const int jrow = jb * 256;

        // emission pointer: walks h_0, h_1, ... -> tep dir0: 0..SS-1, dir1: SS-1..0
        unsigned short* fpx = fp + ((size_t)(b0 + qd) * SS + (dir ? SS - 1 : 0)) * 64
                            + ct * 16 + n;
        const ptrdiff_t fpd = dir ? -64 : 64;

        // e <- emb frags for A rows of group G (lane's row = (jb, 4G+tau))
        auto loadfrag = [&](int G, bf16x8* e) {
            const int t  = 4 * G + tau;
            const int te = dir ? (SS - 1 - t) : t;
            const int xi = xsh[jrow + te];
            const unsigned short* er = ebf + (size_t)xi * EE + qd * 8;
            e[0] = *(const bf16x8*)(er);
            e[1] = *(const bf16x8*)(er + 32);
            e[2] = *(const bf16x8*)(er + 64);
            e[3] = *(const bf16x8*)(er + 96);
        };
        // one slot's gx for a whole 4-ts group -> gxb[buf][0..3]
        auto computeS = [&](const bf16x8* e, const bf16x8 (*fx)[4],
                            const float* bs, int gsv, int buf) {
            f32x4 c[4] = { {0,0,0,0}, {0,0,0,0}, {0,0,0,0}, {0,0,0,0} };
            #pragma unroll
            for (int g = 0; g < 4; ++g) {
                #pragma unroll
                for (int kk = 0; kk < 4; ++kk)
                    c[g] = __builtin_amdgcn_mfma_f32_16x16x32_bf16(e[kk], fx[g][kk], c[g], 0, 0, 0);
            }
            #pragma unroll
            for (int r = 0; r < 4; ++r) {
                f32x4 p = { c[0][r] + bs[0], c[1][r] + bs[1],
                            c[2][r] + bs[2], c[3][r] + bs[3] };
                *(f32x4*)&gxb[buf][r][gsv] = p;
            }
        };
        // project h_{ts-1} (lives in hbuf[ts&1], stable during interval ts)
        auto projx = [&](int ts) {
            f32x4 pp = (f32x4){0.f, 0.f, 0.f, 0.f};
            #pragma unroll
            for (int kk = 0; kk < 4; ++kk) {
                const bf16x8 a = *(const bf16x8*)&hbuf[ts & 1][((kk * 4 + qd) * 16 + n) * 8];
                pp = __builtin_amdgcn_mfma_f32_16x16x32_bf16(a, wbx[kk], pp, 0, 0, 0);
            }
            *fpx = (unsigned short)f2bf(pp[0]);
            fpx += fpd;
        };

        __syncthreads();   // B1: xsh visible
        bf16x8 eA[4], eB[4];
        loadfrag(0, eA);                       // group 0 frags
        computeS(eA, fx0, bs0, gs0, 0);        // gxb[0] <- group 0 (pre-loop stall, once)
        computeS(eA, fx1, bs1, gs1, 0);
        loadfrag(1, eB);                       // group 1 frags
        __syncthreads();   // B2

        // group G covers intervals ts=4G..4G+3. Produce gx group G+1 (slot0 in
        // I0, slot1 in I1), prefetch frags G+2 (I0), and project h_{ts-1} each
        // interval (skip ts=0: no h_{-1}).
        auto xgroup = [&](int G, bf16x8* use, bf16x8* pre) {
            const int t0 = 4 * G;
            if (G + 2 < SS / 4) loadfrag(G + 2, pre);
            if (G + 1 < SS / 4) computeS(use, fx0, bs0, gs0, (G + 1) & 1);
            if (t0 > 0) projx(t0);
            bar_lds();
            if (G + 1 < SS / 4) computeS(use, fx1, bs1, gs1, (G + 1) & 1);
            projx(t0 + 1);
            bar_lds();
            projx(t0 + 2);
            bar_lds();
            projx(t0 + 3);
            bar_lds();
        };
        for (int G = 0; G < SS / 4; G += 2) {
            xgroup(G,     eB, eA);
            xgroup(G + 1, eA, eB);
        }
        projx(SS);   // h_{SS-1} (hbuf[0], SS even)
    }
}

// ---------------- kernel 2: CRF fwd/bwd split + gold + reduce (R5 version) ----------------
// Wave 0: alpha over t=0..127; wave 1: beta (transposed trans) over t=255..128
// + gold. fwd = LSE_i(alpha_127 + beta_127). 1024 waves = 1/SIMD machine-wide.
__global__ __launch_bounds__(128, 1) void crf_k(
    const unsigned short* __restrict__ fpF, const unsigned short* __restrict__ fpB,
    const float* __restrict__ bout, const int* __restrict__ y,
    const float* __restrict__ trans, float* __restrict__ out)
{
    const int tid = threadIdx.x;
    const int wv = tid >> 6;          // 0 = alpha wave, 1 = beta+gold wave
    const int j = tid & 63;
    const int b = blockIdx.x;
    const size_t bS = (size_t)b * SS;
    const bool valid = (j < LL);
    const int  jr = valid ? j : (LL - 1);
    const float L2E = 1.44269504f, LN2 = 0.69314718f;

    __shared__ float exch[64];
    __shared__ float gshare;

    // per-lane transition table (log2-exponentiated):
    //   wave 0 (alpha): row jr -> etr[i] = 2^(T[jr,i]*L2E)
    //   wave 1 (beta):  col jr -> etr[i] = 2^(T[i,jr]*L2E)
    float etr[LL];
    #pragma unroll
    for (int i = 0; i < LL; ++i) {
        const float t = wv ? trans[i * LL + jr] : trans[jr * LL + i];
        etr[i] = valid ? __builtin_amdgcn_exp2f(t * L2E) : 0.0f;
    }
    const float bo = valid ? bout[jr] : 0.0f;

    // state (log2 domain): alpha for wave 0, beta for wave 1
    float st;
    if (wv == 0) st = valid ? ((j == STARTL) ? 0.0f : -10000.0f * L2E) : -1e30f;
    else         st = valid ? trans[STOPL * LL + jr] * L2E : -1e30f;
    float Kn = 0.0f;   // lagged stabilizer

    // emission stream: wave 0 ascending t=0.., wave 1 descending t=255..
    auto tAt = [&](int u) { return wv ? (SS - 1 - u) : u; };

    float fF[8], fB[8];
    #pragma unroll
    for (int q = 0; q < 8; ++q) {
        const int t = tAt(q);
        fF[q] = bf2f(fpF[(bS + t) * 64 + j]);
        fB[q] = bf2f(fpB[(bS + t) * 64 + j]);
    }

    for (int u0 = 0; u0 < SS / 2; u0 += 8) {
        float nF[8], nB[8];
        #pragma unroll
        for (int q = 0; q < 8; ++q) { nF[q] = 0.0f; nB[q] = 0.0f; }
        if (u0 + 8 < SS / 2) {
            #pragma unroll
            for (int q = 0; q < 8; ++q) {
                const int t = tAt(u0 + 8 + q);
                nF[q] = bf2f(fpF[(bS + t) * 64 + j]);
                nB[q] = bf2f(fpB[(bS + t) * 64 + j]);
            }
        }
        float fs[8];
        #pragma unroll
        for (int q = 0; q < 8; ++q) fs[q] = (fF[q] + fB[q] + bo) * L2E;

        #pragma unroll
        for (int u = 0; u < 8; ++u) {
            if (wv == 0) {
                // alpha[j] <- fs[j] + LSE_i(alpha[i] + T[j,i])
                const float Kc = Kn;
                const float ea = __builtin_amdgcn_exp2f(st - Kc);
                Kn = fmaxf(rlane(st, 1), rlane(st, STARTL));
                float d0 = 0.f, d1 = 0.f, d2 = 0.f, d3 = 0.f;
                float d4 = 0.f, d5 = 0.f, d6 = 0.f, d7 = 0.f;
                #pragma unroll
                for (int i = 0; i < 56; i += 8) {
                    d0 += etr[i]     * rlane(ea, i);
                    d1 += etr[i + 1] * rlane(ea, i + 1);
                    d2 += etr[i + 2] * rlane(ea, i + 2);
                    d3 += etr[i + 3] * rlane(ea, i + 3);
                    d4 += etr[i + 4] * rlane(ea, i + 4);
                    d5 += etr[i + 5] * rlane(ea, i + 5);
                    d6 += etr[i + 6] * rlane(ea, i + 6);
                    d7 += etr[i + 7] * rlane(ea, i + 7);
                }
                d0 += etr[56] * rlane(ea, 56);
                d1 += etr[57] * rlane(ea, 57);
                d2 += etr[58] * rlane(ea, 58);
                const float dot = ((d0 + d1) + (d2 + d3)) + ((d4 + d5) + (d6 + d7));
                st = fs[u] + Kc + __builtin_amdgcn_logf(dot);   // v_log_f32 = log2
            } else {
                // beta[i] <- LSE_j( (fs[j] + beta[j]) + T[j,i] )
                const float g = fs[u] + st;
                const float Kc = Kn;
                const float eg = __builtin_amdgcn_exp2f(g - Kc);
                Kn = rlane(g, 1);
                float d0 = 0.f, d1 = 0.f, d2 = 0.f, d3 = 0.f;
                float d4 = 0.f, d5 = 0.f, d6 = 0.f, d7 = 0.f;
                #pragma unroll
                for (int i = 0; i < 56; i += 8) {
                    d0 += etr[i]     * rlane(eg, i);
                    d1 += etr[i + 1] * rlane(eg, i + 1);
                    d2 += etr[i + 2] * rlane(eg, i + 2);
                    d3 += etr[i + 3] * rlane(eg, i + 3);
                    d4 += etr[i + 4] * rlane(eg, i + 4);
                    d5 += etr[i + 5] * rlane(eg, i + 5);
                    d6 += etr[i + 6] * rlane(eg, i + 6);
                    d7 += etr[i + 7] * rlane(eg, i + 7);
                }
                d0 += etr[56] * rlane(eg, 56);
                d1 += etr[57] * rlane(eg, 57);
                d2 += etr[58] * rlane(eg, 58);
                const float dot = ((d0 + d1) + (d2 + d3)) + ((d4 + d5) + (d6 + d7));
                st = Kc + __builtin_amdgcn_logf(dot);
            }
        }
        #pragma unroll
        for (int q = 0; q < 8; ++q) { fF[q] = nF[q]; fB[q] = nB[q]; }
    }

    if (wv == 1) {
        // gold path score (whole 0..255 range, 64 lanes x 4)
        float g = 0.0f;
        #pragma unroll
        for (int q = 0; q < 4; ++q) {
            const int t  = q * 64 + j;
            const int yt = y[bS + t];
            const int yp = t ? y[bS + t - 1] : STARTL;
            g += bf2f(fpF[(bS + t) * 64 + yt]) + bf2f(fpB[(bS + t) * 64 + yt])
               + bout[yt] + trans[yt * LL + yp];
        }
        g = wsum64(g);
        if (j == 0) {
            g += trans[STOPL * LL + y[bS + SS - 1]];
            gshare = g;
        }
        exch[j] = st;      // beta_127 (log2)
    }
    __syncthreads();
    if (wv == 0) {
        // fwd = LN2 * LSE2_i(alpha_127[i] + beta_127[i])
        const float v2 = valid ? (st + exch[j]) : -1e30f;
        const float m2 = wmax64(v2);
        const float s  = wsum64(__builtin_amdgcn_exp2f(v2 - m2));
        const float fwd = LN2 * (m2 + __builtin_amdgcn_logf(s));
        if (j == 0) atomicAdd(out, fwd - gshare);
    }
}

// ---------------- launcher ----------------
extern "C" void kernel_launch(void* const* d_in, const int* in_sizes, int n_in,
                              void* d_out, int out_size, void* d_ws, size_t ws_size,
                              hipStream_t stream)
{
    (void)in_sizes; (void)n_in; (void)out_size; (void)ws_size;
    const int*   x      = (const int*)  d_in[0];
    const int*   y      = (const int*)  d_in[1];
    const float* embed  = (const float*)d_in[2];
    const float* Wih_f  = (const float*)d_in[3];
    const float* Whh_f  = (const float*)d_in[4];
    const float* bih_f  = (const float*)d_in[5];
    const float* bhh_f  = (const float*)d_in[6];
    const float* Wih_b  = (const float*)d_in[7];
    const float* Whh_b  = (const float*)d_in[8];
    const float* bih_b  = (const float*)d_in[9];
    const float* bhh_b  = (const float*)d_in[10];
    const float* Wout   = (const float*)d_in[11];
    const float* bout   = (const float*)d_in[12];
    const float* trans  = (const float*)d_in[13];
    const float* h0     = (const float*)d_in[14];
    const float* c0     = (const float*)d_in[15];

    const size_t MiB = 1ull << 20;
    unsigned short* fpF  = (unsigned short*)d_ws;                                   // 16 MiB
    unsigned short* fpB  = (unsigned short*)((char*)d_ws + 16 * MiB);               // 16 MiB
    unsigned short* ebf  = (unsigned short*)((char*)d_ws + 32 * MiB);               // 12.8 MB
    unsigned short* wix  = (unsigned short*)((char*)d_ws + 45 * MiB);               // 256 KiB
    unsigned short* whb  = (unsigned short*)((char*)d_ws + 45 * MiB + 256 * 1024);  // 256 KiB
    float*          bsum = (float*)((char*)d_ws + 45 * MiB + 512 * 1024);           // 4 KiB

    hipMemsetAsync(d_out, 0, sizeof(float), stream);
    conv_k<<<2048, 256, 0, stream>>>(embed, Wih_f, Wih_b, Whh_f, Whh_b,
                                     bih_f, bhh_f, bih_b, bhh_b,
                                     ebf, wix, whb, bsum);
    lstm_f<<<256, 512, 0, stream>>>(x, ebf, wix, whb, bsum, h0, c0, Wout,
                                    fpF, fpB);
    crf_k<<<BB, 128, 0, stream>>>(fpF, fpB, bout, y, trans, (float*)d_out);
}